// Round 18
// baseline (410.721 us; speedup 1.0000x reference)
//
#include <hip/hip_runtime.h>
#include <hip/hip_bf16.h>

// Problem constants (B=4, T=4096, C=1024, NH=16, DH=128, DQKV=2048, DR=256)
#define TB 4
#define TT 4096
#define TC 1024
#define TNH 16
#define TDH 128
#define TDQKV 2048
#define TDR 256
#define RB 4096               // rows per batch
#define ROWS (TB*TT)          // 16384

typedef __attribute__((ext_vector_type(8))) short bfx8;
typedef __attribute__((ext_vector_type(4))) float fx4;
typedef __attribute__((address_space(1))) const unsigned char GAS;
typedef __attribute__((address_space(3))) unsigned char LAS;

__device__ __forceinline__ unsigned short f2b(float f) {
    unsigned int u = __float_as_uint(f);
    unsigned int r = (u + 0x7fffu + ((u >> 16) & 1u)) >> 16;   // RNE
    return (unsigned short)r;
}
__device__ __forceinline__ float b2f(unsigned short h) {
    return __uint_as_float(((unsigned int)h) << 16);
}
__device__ __forceinline__ float sigm(float x) {
    return 1.0f / (1.0f + __expf(-x));
}
// bijective XCD swizzle (all our grids have nwg % 8 == 0)
__device__ __forceinline__ int xcd_swz(int hw, int nwg) {
    int q = nwg >> 3;
    return (hw & 7) * q + (hw >> 3);
}
// pack 4 bf16 (as ushorts) into a u64 for NT vector store
__device__ __forceinline__ unsigned long long pack4(unsigned short a, unsigned short b,
                                                    unsigned short c, unsigned short d) {
    return (unsigned long long)a | ((unsigned long long)b << 16) |
           ((unsigned long long)c << 32) | ((unsigned long long)d << 48);
}

// ---------------- fused setup: 4 weight cvts + rope table, one launch ----------------
__global__ __launch_bounds__(256) void setup_all(const float* __restrict__ wq1, unsigned short* __restrict__ w1b,
                                                 const float* __restrict__ wq2, unsigned short* __restrict__ w2b,
                                                 const float* __restrict__ wc1, unsigned short* __restrict__ wp1b,
                                                 const float* __restrict__ wc2, unsigned short* __restrict__ wp2b,
                                                 float* __restrict__ ct, float* __restrict__ st) {
    int blk = blockIdx.x;
    if (blk < 2816) {
        const float* in; unsigned short* out; int base;
        if (blk < 256)       { in = wq1; out = w1b;  base = blk; }
        else if (blk < 1792) { in = wq2; out = w2b;  base = blk - 256; }
        else if (blk < 2304) { in = wc1; out = wp1b; base = blk - 1792; }
        else                 { in = wc2; out = wp2b; base = blk - 2304; }
        int i = (base * 256 + threadIdx.x) * 4;
        float4 v = *(const float4*)(in + i);
        out[i + 0] = f2b(v.x);
        out[i + 1] = f2b(v.y);
        out[i + 2] = f2b(v.z);
        out[i + 3] = f2b(v.w);
    } else {
        int i = (blk - 2816) * 256 + threadIdx.x;   // < T*32
        int t = i >> 5, j = i & 31;
        float fr = exp2f(-10.0f * (float)j / 31.0f);   // (1/1024)^(j/31)
        float th = (float)t * fr;
        ct[i] = cosf(th);
        st[i] = sinf(th);
    }
}

// ---------------- RMSNorm(x) -> bf16, one block per row of 1024 ----------------
__global__ __launch_bounds__(256) void rmsnorm_x(const float* __restrict__ x,
                                                 unsigned short* __restrict__ xn) {
    int row = blockIdx.x;
    int tid = threadIdx.x;
    float4 v = *(const float4*)(x + (size_t)row * TC + tid * 4);
    float ss = v.x * v.x + v.y * v.y + v.z * v.z + v.w * v.w;
    #pragma unroll
    for (int o = 32; o > 0; o >>= 1) ss += __shfl_xor(ss, o);
    __shared__ float red[4];
    if ((tid & 63) == 0) red[tid >> 6] = ss;
    __syncthreads();
    float tot = red[0] + red[1] + red[2] + red[3];
    float sc = rsqrtf(tot * (1.0f / TC) + 1.1920929e-7f);
    unsigned short* o = xn + (size_t)row * TC + tid * 4;
    o[0] = f2b(v.x * sc); o[1] = f2b(v.y * sc); o[2] = f2b(v.z * sc); o[3] = f2b(v.w * sc);
}

// ---------------- gemm2k: 128x128 bf16 GEMM (R11-proven), NT scatter to head-major qkv ---
__global__ __launch_bounds__(256) void gemm2k(const unsigned short* __restrict__ A,
                                              const unsigned short* __restrict__ Bm,
                                              unsigned short* __restrict__ C,
                                              int K, size_t slab) {
    __shared__ unsigned short As[2][128 * 32];
    __shared__ unsigned short Bs[2][128 * 32];
    const int m0 = blockIdx.y * 128;
    const int n0 = blockIdx.x * 128;
    const int tid = threadIdx.x;
    const int lane = tid & 63;
    const int w = tid >> 6;
    const int wr = w >> 1, wc = w & 1;
    const int r16 = lane & 15;
    const int kk = (lane >> 4) * 8;
    const int l4 = lane >> 2;
    const int c8 = (lane & 3) * 8;
    const int nk = K >> 5;
    fx4 acc[4][4] = {};

    auto stage = [&](int buf, int k0) {
        #pragma unroll
        for (int i = 0; i < 2; ++i) {
            int rr = (w + 4 * i) * 16 + l4;
            const unsigned short* ga = A + (size_t)(m0 + rr) * TDR + k0 + c8;
            const unsigned short* gb = Bm + (size_t)(n0 + rr) * K + k0 + c8;
            __builtin_amdgcn_global_load_lds((GAS*)ga, (LAS*)&As[buf][(w + 4 * i) * 512], 16, 0, 0);
            __builtin_amdgcn_global_load_lds((GAS*)gb, (LAS*)&Bs[buf][(w + 4 * i) * 512], 16, 0, 0);
        }
    };

    stage(0, 0);
    __syncthreads();
    int buf = 0;
    for (int ks = 0; ks < nk; ++ks) {
        if (ks + 1 < nk) stage(buf ^ 1, (ks + 1) * 32);
        bfx8 af[4], bfr[4];
        #pragma unroll
        for (int mi = 0; mi < 4; mi++) af[mi] = *(const bfx8*)&As[buf][(wr * 64 + mi * 16 + r16) * 32 + kk];
        #pragma unroll
        for (int ni = 0; ni < 4; ni++) bfr[ni] = *(const bfx8*)&Bs[buf][(wc * 64 + ni * 16 + r16) * 32 + kk];
        #pragma unroll
        for (int mi = 0; mi < 4; mi++)
            #pragma unroll
            for (int ni = 0; ni < 4; ni++)
                acc[mi][ni] = __builtin_amdgcn_mfma_f32_16x16x32_bf16(af[mi], bfr[ni], acc[mi][ni], 0, 0, 0);
        __syncthreads();
        buf ^= 1;
    }

    // scalar scatter (R11-proven pattern), non-temporal: qkv is streamed, not L2-reused here
    const int rg = lane >> 4;
    #pragma unroll
    for (int mi = 0; mi < 4; mi++)
        #pragma unroll
        for (int ni = 0; ni < 4; ni++) {
            int col = n0 + wc * 64 + ni * 16 + r16;
            int head = col >> 7;
            unsigned short* dst = C + (size_t)head * slab + (col & 127);
            #pragma unroll
            for (int r = 0; r < 4; r++) {
                int row = m0 + wr * 64 + mi * 16 + rg * 4 + r;
                __builtin_nontemporal_store(f2b(acc[mi][ni][r]), dst + (size_t)row * 128);
            }
        }
}

// ---------------- 128(M)x64(N) skinny-N GEMM, transposed-output mfma, ushort4 stores -----
template <int EPI, int NX>
__global__ __launch_bounds__(256) void gemm_sk(const unsigned short* __restrict__ A, int lda,
                                               const unsigned short* __restrict__ Bm,
                                               unsigned short* __restrict__ C, int ldc,
                                               int K) {
    __shared__ unsigned short As[2][128 * 32];
    __shared__ unsigned short Bs[2][64 * 32];
    const int lg = xcd_swz(blockIdx.x, gridDim.x);
    const int n0 = (lg % NX) * 64;
    const int m0 = (lg / NX) * 128;
    const int tid = threadIdx.x;
    const int lane = tid & 63;
    const int w = tid >> 6;
    const int wr = w >> 1, wc = w & 1;       // wave tile: 64 rows x 32 cols
    const int r16 = lane & 15;
    const int rg = lane >> 4;
    const int kk = rg * 8;
    const int l4 = lane >> 2;
    const int c8 = (lane & 3) * 8;
    const int nk = K >> 5;
    fx4 acc[4][2] = {};

    auto stage = [&](int buf, int k0) {
        #pragma unroll
        for (int i = 0; i < 2; ++i) {
            int rr = (w + 4 * i) * 16 + l4;
            const unsigned short* ga = A + (size_t)(m0 + rr) * lda + k0 + c8;
            __builtin_amdgcn_global_load_lds((GAS*)ga, (LAS*)&As[buf][(w + 4 * i) * 512], 16, 0, 0);
        }
        const unsigned short* gb = Bm + (size_t)(n0 + w * 16 + l4) * K + k0 + c8;
        __builtin_amdgcn_global_load_lds((GAS*)gb, (LAS*)&Bs[buf][w * 512], 16, 0, 0);
    };

    stage(0, 0);
    __syncthreads();
    int buf = 0;
    for (int ks = 0; ks < nk; ++ks) {
        if (ks + 1 < nk) stage(buf ^ 1, (ks + 1) * 32);
        bfx8 af[4], bfr[2];
        #pragma unroll
        for (int mi = 0; mi < 4; mi++) af[mi] = *(const bfx8*)&As[buf][(wr * 64 + mi * 16 + r16) * 32 + kk];
        #pragma unroll
        for (int ni = 0; ni < 2; ni++) bfr[ni] = *(const bfx8*)&Bs[buf][(wc * 32 + ni * 16 + r16) * 32 + kk];
        #pragma unroll
        for (int mi = 0; mi < 4; mi++)
            #pragma unroll
            for (int ni = 0; ni < 2; ni++)
                acc[mi][ni] = __builtin_amdgcn_mfma_f32_16x16x32_bf16(bfr[ni], af[mi], acc[mi][ni], 0, 0, 0);
        __syncthreads();
        buf ^= 1;
    }

    #pragma unroll
    for (int mi = 0; mi < 4; mi++) {
        int m = m0 + wr * 64 + mi * 16 + r16;
        #pragma unroll
        for (int ni = 0; ni < 2; ni++) {
            int n = n0 + wc * 32 + ni * 16 + rg * 4;
            ushort4 o;
            #pragma unroll
            for (int j = 0; j < 4; ++j) {
                float v = acc[mi][ni][j];
                if (EPI == 1) { v = fmaxf(v, 0.0f); v *= v; }
                ((unsigned short*)&o)[j] = f2b(v);
            }
            *(ushort4*)(C + (size_t)m * ldc + n) = o;
        }
    }
}

// ---------------- gemm4 fused with final, 64x64 tiles, transposed mfma, float4 epilogue ---
__global__ __launch_bounds__(256) void gemm4f64(const unsigned short* __restrict__ A,
                                                const unsigned short* __restrict__ Wm,
                                                const float* __restrict__ x,
                                                float* __restrict__ out) {
    __shared__ unsigned short As[2][64 * 32];
    __shared__ unsigned short Bu[2][64 * 32];
    __shared__ unsigned short Bg[2][64 * 32];
    const int hw = blockIdx.y * gridDim.x + blockIdx.x;
    const int lg = xcd_swz(hw, gridDim.x * gridDim.y);   // 16 x 256 = 4096 blocks
    const int n0 = (lg & 15) * 64;            // u col block within 1024
    const int m0 = (lg >> 4) * 64;
    const int tid = threadIdx.x;
    const int lane = tid & 63;
    const int w = tid >> 6;
    const int wr = w >> 1, wc = w & 1;
    const int r16 = lane & 15;
    const int rg = lane >> 4;
    const int kk = rg * 8;
    const int l4 = lane >> 2;
    const int c8 = (lane & 3) * 8;
    fx4 accu[2][2] = {};
    fx4 accg[2][2] = {};

    auto stage = [&](int buf, int k0) {
        int rr = w * 16 + l4;
        const unsigned short* ga = A + (size_t)(m0 + rr) * TDR + k0 + c8;
        const unsigned short* gu = Wm + (size_t)(n0 + rr) * TDR + k0 + c8;
        const unsigned short* gg = Wm + (size_t)(1024 + n0 + rr) * TDR + k0 + c8;
        __builtin_amdgcn_global_load_lds((GAS*)ga, (LAS*)&As[buf][w * 512], 16, 0, 0);
        __builtin_amdgcn_global_load_lds((GAS*)gu, (LAS*)&Bu[buf][w * 512], 16, 0, 0);
        __builtin_amdgcn_global_load_lds((GAS*)gg, (LAS*)&Bg[buf][w * 512], 16, 0, 0);
    };

    stage(0, 0);
    __syncthreads();
    int buf = 0;
    for (int ks = 0; ks < 8; ++ks) {          // K = 256
        if (ks + 1 < 8) stage(buf ^ 1, (ks + 1) * 32);
        bfx8 af[2], bu[2], bg[2];
        #pragma unroll
        for (int mi = 0; mi < 2; mi++) af[mi] = *(const bfx8*)&As[buf][(wr * 32 + mi * 16 + r16) * 32 + kk];
        #pragma unroll
        for (int ni = 0; ni < 2; ni++) {
            bu[ni] = *(const bfx8*)&Bu[buf][(wc * 32 + ni * 16 + r16) * 32 + kk];
            bg[ni] = *(const bfx8*)&Bg[buf][(wc * 32 + ni * 16 + r16) * 32 + kk];
        }
        #pragma unroll
        for (int mi = 0; mi < 2; mi++)
            #pragma unroll
            for (int ni = 0; ni < 2; ni++) {
                accu[mi][ni] = __builtin_amdgcn_mfma_f32_16x16x32_bf16(bu[ni], af[mi], accu[mi][ni], 0, 0, 0);
                accg[mi][ni] = __builtin_amdgcn_mfma_f32_16x16x32_bf16(bg[ni], af[mi], accg[mi][ni], 0, 0, 0);
            }
        __syncthreads();
        buf ^= 1;
    }

    #pragma unroll
    for (int mi = 0; mi < 2; mi++) {
        int m = m0 + wr * 32 + mi * 16 + r16;
        #pragma unroll
        for (int ni = 0; ni < 2; ni++) {
            int n = n0 + wc * 32 + ni * 16 + rg * 4;
            size_t base = (size_t)m * TC + n;
            float4 xv = *(const float4*)(x + base);
            float4 o;
            #pragma unroll
            for (int j = 0; j < 4; ++j) {
                float u = accu[mi][ni][j];
                float g = accg[mi][ni][j];
                (&o.x)[j] = (&xv.x)[j] + u * (g * sigm(g));
            }
            *(float4*)(out + base) = o;
        }
    }
}

// ---------------- fused post (R11-proven): q/k RMSNorm+RoPE, p=sigm(k)*v, 32-t seg sums --
__global__ __launch_bounds__(256) void post64(unsigned short* __restrict__ qkv,
                                              const float* __restrict__ ct,
                                              const float* __restrict__ st,
                                              float* __restrict__ part,
                                              int ntiles, int nseg) {
    const int blk = blockIdx.x;
    const int tile = blk % ntiles, h = blk / ntiles;
    const size_t slab = (size_t)ntiles * 64 * 128;
    const int g = threadIdx.x >> 4, l16 = threadIdx.x & 15;
    const int d0 = l16 * 4;
    unsigned short* qs = qkv + (size_t)h * slab;
    unsigned short* ks = qkv + (size_t)(16 + h) * slab;
    unsigned short* vs = qkv + (size_t)(32 + h) * slab;
    __shared__ float psum[2][16][128];
    float acc0[2][4] = {};
    float acc1[2][4] = {};

    #pragma unroll
    for (int p = 0; p < 4; ++p) {
        const int r = tile * 64 + p * 16 + g;      // row within chunk
        const int t = r & (TT - 1);                // time within batch (rope index)
        const size_t lo = (size_t)r * 128 + d0, hi = lo + 64;
        ushort4 q1 = *(const ushort4*)(qs + lo);
        ushort4 q2 = *(const ushort4*)(qs + hi);
        ushort4 k1 = *(const ushort4*)(ks + lo);
        ushort4 k2 = *(const ushort4*)(ks + hi);
        float qa[8] = {b2f(q1.x), b2f(q1.y), b2f(q1.z), b2f(q1.w),
                       b2f(q2.x), b2f(q2.y), b2f(q2.z), b2f(q2.w)};
        float ka[8] = {b2f(k1.x), b2f(k1.y), b2f(k1.z), b2f(k1.w),
                       b2f(k2.x), b2f(k2.y), b2f(k2.z), b2f(k2.w)};
        float ssq = 0.0f, ssk = 0.0f;
        #pragma unroll
        for (int j = 0; j < 8; ++j) { ssq += qa[j] * qa[j]; ssk += ka[j] * ka[j]; }
        #pragma unroll
        for (int o = 8; o > 0; o >>= 1) {
            ssq += __shfl_xor(ssq, o);
            ssk += __shfl_xor(ssk, o);
        }
        float qsc = rsqrtf(ssq * (1.0f / TDH) + 1.1920929e-7f);
        float ksc = rsqrtf(ssk * (1.0f / TDH) + 1.1920929e-7f);
        float c[4], s[4];
        if (l16 < 8) {
            float4 cv = *(const float4*)(ct + t * 32 + d0);
            float4 sv = *(const float4*)(st + t * 32 + d0);
            c[0] = cv.x; c[1] = cv.y; c[2] = cv.z; c[3] = cv.w;
            s[0] = sv.x; s[1] = sv.y; s[2] = sv.z; s[3] = sv.w;
        } else {
            c[0] = c[1] = c[2] = c[3] = 1.0f;
            s[0] = s[1] = s[2] = s[3] = 0.0f;
        }
        ushort4 v1 = *(const ushort4*)(vs + lo);
        ushort4 v2 = *(const ushort4*)(vs + hi);
        float va[8] = {b2f(v1.x), b2f(v1.y), b2f(v1.z), b2f(v1.w),
                       b2f(v2.x), b2f(v2.y), b2f(v2.z), b2f(v2.w)};
        unsigned short qo1p[4], qo2p[4], po1p[4], po2p[4];
        const int h2 = p >> 1;
        #pragma unroll
        for (int j = 0; j < 4; ++j) {
            float z1q = qa[j] * qsc, z2q = qa[4 + j] * qsc;
            float z1k = ka[j] * ksc, z2k = ka[4 + j] * ksc;
            float qlo = z1q * c[j] + z2q * s[j];
            float qhi = z2q * c[j] - z1q * s[j];
            float klo = z1k * c[j] + z2k * s[j];
            float khi = z2k * c[j] - z1k * s[j];
            float plo = sigm(klo) * va[j];
            float phi = sigm(khi) * va[4 + j];
            qo1p[j] = f2b(qlo); qo2p[j] = f2b(qhi);
            po1p[j] = f2b(plo); po2p[j] = f2b(phi);
            acc0[h2][j] += plo;
            acc1[h2][j] += phi;
        }
        __builtin_nontemporal_store(pack4(qo1p[0], qo1p[1], qo1p[2], qo1p[3]),
                                    (unsigned long long*)(qs + lo));
        __builtin_nontemporal_store(pack4(qo2p[0], qo2p[1], qo2p[2], qo2p[3]),
                                    (unsigned long long*)(qs + hi));
        __builtin_nontemporal_store(pack4(po1p[0], po1p[1], po1p[2], po1p[3]),
                                    (unsigned long long*)(ks + lo));   // p overwrites k
        __builtin_nontemporal_store(pack4(po2p[0], po2p[1], po2p[2], po2p[3]),
                                    (unsigned long long*)(ks + hi));
    }
    #pragma unroll
    for (int h2 = 0; h2 < 2; ++h2) {
        *(float4*)&psum[h2][g][d0]      = *(float4*)acc0[h2];
        *(float4*)&psum[h2][g][64 + d0] = *(float4*)acc1[h2];
    }
    __syncthreads();
    const int h2 = threadIdx.x >> 7, d = threadIdx.x & 127;
    float tot = 0.0f;
    #pragma unroll
    for (int gg = 0; gg < 16; ++gg) tot += psum[h2][gg][d];
    part[((size_t)h * nseg + tile * 2 + h2) * 128 + d] = tot;
}

// ---------------- phase B: exclusive prefix, one chain per (h, batch, d) ----------------
__global__ __launch_bounds__(256) void scanB2(float* __restrict__ part, int cb) {
    int idx = blockIdx.x * 256 + threadIdx.x;   // < TNH*cb*128
    int d = idx & 127;
    int hb = idx >> 7;                           // h*cb + batch
    int batch = hb % cb;
    int h = hb / cb;
    int nseg = cb * 128;
    size_t base = ((size_t)h * nseg + (size_t)batch * 128) * 128 + d;
    float run = 0.0f;
    #pragma unroll
    for (int r = 0; r < 4; ++r) {
        float v[32];
        #pragma unroll
        for (int i = 0; i < 32; ++i) v[i] = part[base + (size_t)(r * 32 + i) * 128];
        #pragma unroll
        for (int i = 0; i < 32; ++i) { float tv = v[i]; v[i] = run; run += tv; }
        #pragma unroll
        for (int i = 0; i < 32; ++i) part[base + (size_t)(r * 32 + i) * 128] = v[i];
    }
}

// ---------------- phase C: y = relu(q) * cumsum(p) -> y row-major (NT store) -------------
__global__ __launch_bounds__(256) void scanC3(const unsigned short* __restrict__ qkv,
                                              const float* __restrict__ part,
                                              unsigned short* __restrict__ y,
                                              int nsegblk, int nseg) {
    const int bseg = blockIdx.x % nsegblk, h = blockIdx.x / nsegblk;
    const size_t slab = (size_t)nseg * 32 * 128;
    const int g = threadIdx.x >> 4, l16 = threadIdx.x & 15;
    const int seg = bseg * 16 + g;
    const int d0 = l16 * 8;
    const unsigned short* qp = qkv + (size_t)h * slab;
    const unsigned short* pp = qkv + (size_t)(16 + h) * slab;
    float sum[8];
    const float* pb = part + ((size_t)h * nseg + seg) * 128 + d0;
    *(float4*)&sum[0] = *(const float4*)pb;
    *(float4*)&sum[4] = *(const float4*)(pb + 4);
    #pragma unroll 4
    for (int i = 0; i < 32; ++i) {
        int t = seg * 32 + i;
        size_t off = (size_t)t * 128 + d0;
        bfx8 pv = *(const bfx8*)(pp + off);
        bfx8 qv = *(const bfx8*)(qp + off);
        bfx8 ov;
        #pragma unroll
        for (int j = 0; j < 8; ++j) {
            sum[j] += b2f((unsigned short)pv[j]);
            float q = b2f((unsigned short)qv[j]);
            ov[j] = (short)f2b(fmaxf(q, 0.0f) * sum[j]);
        }
        __builtin_nontemporal_store(ov, (bfx8*)(y + (size_t)t * 2048 + h * 128 + d0));
    }
}

extern "C" void kernel_launch(void* const* d_in, const int* in_sizes, int n_in,
                              void* d_out, int out_size, void* d_ws, size_t ws_size,
                              hipStream_t stream) {
    (void)in_sizes; (void)n_in; (void)out_size;
    const float* x    = (const float*)d_in[0];
    const float* wq1  = (const float*)d_in[1];   // [256,1024]
    const float* wq2  = (const float*)d_in[2];   // [6144,256]
    const float* wc1  = (const float*)d_in[3];   // [256,2048]
    const float* wc2  = (const float*)d_in[4];   // [2048,256]
    float* out = (float*)d_out;

    // pick batches-per-chunk CB by available workspace
    auto need = [](int cb) -> size_t {
        size_t o = 0;
        auto a = [&](size_t b) { o = (o + 255) & ~(size_t)255; o += b; };
        size_t qkvsz = (size_t)cb * RB * 6144 * 2;
        size_t xnsz  = (size_t)ROWS * TC * 2;
        a(qkvsz > xnsz ? qkvsz : xnsz);                 // pool
        a((size_t)ROWS * TDR * 2);                       // hbuf
        a((size_t)TDR * TC * 2);                         // w1b
        a((size_t)3 * TDQKV * TDR * 2);                  // w2b
        a((size_t)TDR * TDQKV * 2);                      // wp1b
        a((size_t)2 * TC * TDR * 2);                     // wp2b
        a((size_t)TT * 32 * 4);                          // ct
        a((size_t)TT * 32 * 4);                          // st
        a((size_t)TNH * (cb * RB / 32) * 128 * 4);       // part
        return o;
    };
    int CB = (ws_size >= need(4)) ? 4 : (ws_size >= need(2)) ? 2 : 1;
    const int TR = CB * RB;            // rows per chunk
    const int NCH = TB / CB;           // chunks
    const int nseg = TR / 32;
    const int ntiles = TR / 64;

    char* ws = (char*)d_ws;
    size_t off = 0;
    auto alloc = [&](size_t bytes) -> void* {
        off = (off + 255) & ~(size_t)255;
        void* p = ws + off;
        off += bytes;
        return p;
    };
    size_t qkvsz = (size_t)TR * 6144 * 2;
    size_t xnsz  = (size_t)ROWS * TC * 2;
    char* pool = (char*)alloc(qkvsz > xnsz ? qkvsz : xnsz);
    unsigned short* qkvb = (unsigned short*)pool;              // head-major: 48 slabs [TR][128]
    unsigned short* xn   = (unsigned short*)pool;              // alias (ROWS x 1024)
    unsigned short* t1   = (unsigned short*)pool;              // alias (ROWS x 256)
    unsigned short* hbuf = (unsigned short*)alloc((size_t)ROWS * TDR * 2);
    unsigned short* w1b  = (unsigned short*)alloc((size_t)TDR * TC * 2);
    unsigned short* w2b  = (unsigned short*)alloc((size_t)3 * TDQKV * TDR * 2);
    unsigned short* wp1b = (unsigned short*)alloc((size_t)TDR * TDQKV * 2);
    unsigned short* wp2b = (unsigned short*)alloc((size_t)2 * TC * TDR * 2);
    float* ct   = (float*)alloc((size_t)TT * 32 * 4);
    float* st   = (float*)alloc((size_t)TT * 32 * 4);
    float* part = (float*)alloc((size_t)TNH * nseg * 128 * 4);
    unsigned short* ybuf = (unsigned short*)d_out;             // y lives in d_out (bf16 16384x2048)

    // fused setup (one launch)
    setup_all<<<3328, 256, 0, stream>>>(wq1, w1b, wq2, w2b, wc1, wp1b, wc2, wp2b, ct, st);

    // all-rows: rmsnorm + gemm1 (xn -> h) with relu^2
    rmsnorm_x<<<ROWS, 256, 0, stream>>>(x, xn);
    gemm_sk<1, 4><<<(ROWS / 128) * (TDR / 64), 256, 0, stream>>>(
        xn, TC, w1b, hbuf, TDR, TC);

    // per-chunk: gemm2k (NT head-major scatter) -> post64 -> scanB2 -> scanC3
    for (int c = 0; c < NCH; ++c) {
        gemm2k<<<dim3(6144 / 128, TR / 128), 256, 0, stream>>>(
            hbuf + (size_t)c * TR * TDR, w2b, qkvb, TDR, (size_t)TR * 128);
        post64<<<TNH * ntiles, 256, 0, stream>>>(qkvb, ct, st, part, ntiles, nseg);
        scanB2<<<(TNH * CB * 128) / 256, 256, 0, stream>>>(part, CB);
        scanC3<<<TNH * (nseg / 16), 256, 0, stream>>>(
            qkvb, part, ybuf + (size_t)c * TR * 2048, nseg / 16, nseg);
    }

    // all-rows tail: gemm3 (y -> t1), fused gemm4+final -> f32 out
    gemm_sk<0, 4><<<(ROWS / 128) * (TDR / 64), 256, 0, stream>>>(
        ybuf, 2048, wp1b, t1, TDR, TDQKV);
    gemm4f64<<<dim3(TC / 64, ROWS / 64), 256, 0, stream>>>(t1, wp2b, x, out);
}

// Round 19
// 351.166 us; speedup vs baseline: 1.1696x; 1.1696x over previous
//
#include <hip/hip_runtime.h>
#include <hip/hip_bf16.h>

// Problem constants (B=4, T=4096, C=1024, NH=16, DH=128, DQKV=2048, DR=256)
#define TB 4
#define TT 4096
#define TC 1024
#define TNH 16
#define TDH 128
#define TDQKV 2048
#define TDR 256
#define RB 4096               // rows per batch
#define ROWS (TB*TT)          // 16384

typedef __attribute__((ext_vector_type(8))) short bfx8;
typedef __attribute__((ext_vector_type(4))) float fx4;
typedef __attribute__((address_space(1))) const unsigned char GAS;
typedef __attribute__((address_space(3))) unsigned char LAS;

__device__ __forceinline__ unsigned short f2b(float f) {
    unsigned int u = __float_as_uint(f);
    unsigned int r = (u + 0x7fffu + ((u >> 16) & 1u)) >> 16;   // RNE
    return (unsigned short)r;
}
__device__ __forceinline__ float b2f(unsigned short h) {
    return __uint_as_float(((unsigned int)h) << 16);
}
__device__ __forceinline__ float sigm(float x) {
    return 1.0f / (1.0f + __expf(-x));
}
// bijective XCD swizzle (all our grids have nwg % 8 == 0)
__device__ __forceinline__ int xcd_swz(int hw, int nwg) {
    int q = nwg >> 3;
    return (hw & 7) * q + (hw >> 3);
}

// ---------------- fused setup: 4 weight cvts + rope table, one launch ----------------
__global__ __launch_bounds__(256) void setup_all(const float* __restrict__ wq1, unsigned short* __restrict__ w1b,
                                                 const float* __restrict__ wq2, unsigned short* __restrict__ w2b,
                                                 const float* __restrict__ wc1, unsigned short* __restrict__ wp1b,
                                                 const float* __restrict__ wc2, unsigned short* __restrict__ wp2b,
                                                 float* __restrict__ ct, float* __restrict__ st) {
    int blk = blockIdx.x;
    if (blk < 2816) {
        const float* in; unsigned short* out; int base;
        if (blk < 256)       { in = wq1; out = w1b;  base = blk; }
        else if (blk < 1792) { in = wq2; out = w2b;  base = blk - 256; }
        else if (blk < 2304) { in = wc1; out = wp1b; base = blk - 1792; }
        else                 { in = wc2; out = wp2b; base = blk - 2304; }
        int i = (base * 256 + threadIdx.x) * 4;
        float4 v = *(const float4*)(in + i);
        out[i + 0] = f2b(v.x);
        out[i + 1] = f2b(v.y);
        out[i + 2] = f2b(v.z);
        out[i + 3] = f2b(v.w);
    } else {
        int i = (blk - 2816) * 256 + threadIdx.x;   // < T*32
        int t = i >> 5, j = i & 31;
        float fr = exp2f(-10.0f * (float)j / 31.0f);   // (1/1024)^(j/31)
        float th = (float)t * fr;
        ct[i] = cosf(th);
        st[i] = sinf(th);
    }
}

// ---------------- RMSNorm(x) -> bf16, one block per row of 1024 ----------------
__global__ __launch_bounds__(256) void rmsnorm_x(const float* __restrict__ x,
                                                 unsigned short* __restrict__ xn) {
    int row = blockIdx.x;
    int tid = threadIdx.x;
    float4 v = *(const float4*)(x + (size_t)row * TC + tid * 4);
    float ss = v.x * v.x + v.y * v.y + v.z * v.z + v.w * v.w;
    #pragma unroll
    for (int o = 32; o > 0; o >>= 1) ss += __shfl_xor(ss, o);
    __shared__ float red[4];
    if ((tid & 63) == 0) red[tid >> 6] = ss;
    __syncthreads();
    float tot = red[0] + red[1] + red[2] + red[3];
    float sc = rsqrtf(tot * (1.0f / TC) + 1.1920929e-7f);
    unsigned short* o = xn + (size_t)row * TC + tid * 4;
    o[0] = f2b(v.x * sc); o[1] = f2b(v.y * sc); o[2] = f2b(v.z * sc); o[3] = f2b(v.w * sc);
}

// ---------------- gemm2: 128x128 bf16 GEMM (R11-proven), plain scatter to head-major ----
__global__ __launch_bounds__(256) void gemm2k(const unsigned short* __restrict__ A,
                                              const unsigned short* __restrict__ Bm,
                                              unsigned short* __restrict__ C,
                                              int K, size_t slab) {
    __shared__ unsigned short As[2][128 * 32];
    __shared__ unsigned short Bs[2][128 * 32];
    const int m0 = blockIdx.y * 128;
    const int n0 = blockIdx.x * 128;
    const int tid = threadIdx.x;
    const int lane = tid & 63;
    const int w = tid >> 6;
    const int wr = w >> 1, wc = w & 1;
    const int r16 = lane & 15;
    const int kk = (lane >> 4) * 8;
    const int l4 = lane >> 2;
    const int c8 = (lane & 3) * 8;
    const int nk = K >> 5;
    fx4 acc[4][4] = {};

    auto stage = [&](int buf, int k0) {
        #pragma unroll
        for (int i = 0; i < 2; ++i) {
            int rr = (w + 4 * i) * 16 + l4;
            const unsigned short* ga = A + (size_t)(m0 + rr) * TDR + k0 + c8;
            const unsigned short* gb = Bm + (size_t)(n0 + rr) * K + k0 + c8;
            __builtin_amdgcn_global_load_lds((GAS*)ga, (LAS*)&As[buf][(w + 4 * i) * 512], 16, 0, 0);
            __builtin_amdgcn_global_load_lds((GAS*)gb, (LAS*)&Bs[buf][(w + 4 * i) * 512], 16, 0, 0);
        }
    };

    stage(0, 0);
    __syncthreads();
    int buf = 0;
    for (int ks = 0; ks < nk; ++ks) {
        if (ks + 1 < nk) stage(buf ^ 1, (ks + 1) * 32);
        bfx8 af[4], bfr[4];
        #pragma unroll
        for (int mi = 0; mi < 4; mi++) af[mi] = *(const bfx8*)&As[buf][(wr * 64 + mi * 16 + r16) * 32 + kk];
        #pragma unroll
        for (int ni = 0; ni < 4; ni++) bfr[ni] = *(const bfx8*)&Bs[buf][(wc * 64 + ni * 16 + r16) * 32 + kk];
        #pragma unroll
        for (int mi = 0; mi < 4; mi++)
            #pragma unroll
            for (int ni = 0; ni < 4; ni++)
                acc[mi][ni] = __builtin_amdgcn_mfma_f32_16x16x32_bf16(af[mi], bfr[ni], acc[mi][ni], 0, 0, 0);
        __syncthreads();
        buf ^= 1;
    }

    // plain scalar scatter (L2 write-combines; NT proved 2.2x write amplification in R18)
    const int rg = lane >> 4;
    #pragma unroll
    for (int mi = 0; mi < 4; mi++)
        #pragma unroll
        for (int ni = 0; ni < 4; ni++) {
            int col = n0 + wc * 64 + ni * 16 + r16;
            int head = col >> 7;
            unsigned short* dst = C + (size_t)head * slab + (col & 127);
            #pragma unroll
            for (int r = 0; r < 4; r++) {
                int row = m0 + wr * 64 + mi * 16 + rg * 4 + r;
                dst[(size_t)row * 128] = f2b(acc[mi][ni][r]);
            }
        }
}

// ---------------- 128(M)x64(N) skinny-N GEMM, transposed-output mfma, ushort4 stores -----
template <int EPI, int NX>
__global__ __launch_bounds__(256) void gemm_sk(const unsigned short* __restrict__ A, int lda,
                                               const unsigned short* __restrict__ Bm,
                                               unsigned short* __restrict__ C, int ldc,
                                               int K) {
    __shared__ unsigned short As[2][128 * 32];
    __shared__ unsigned short Bs[2][64 * 32];
    const int lg = xcd_swz(blockIdx.x, gridDim.x);
    const int n0 = (lg % NX) * 64;
    const int m0 = (lg / NX) * 128;
    const int tid = threadIdx.x;
    const int lane = tid & 63;
    const int w = tid >> 6;
    const int wr = w >> 1, wc = w & 1;       // wave tile: 64 rows x 32 cols
    const int r16 = lane & 15;
    const int rg = lane >> 4;
    const int kk = rg * 8;
    const int l4 = lane >> 2;
    const int c8 = (lane & 3) * 8;
    const int nk = K >> 5;
    fx4 acc[4][2] = {};

    auto stage = [&](int buf, int k0) {
        #pragma unroll
        for (int i = 0; i < 2; ++i) {
            int rr = (w + 4 * i) * 16 + l4;
            const unsigned short* ga = A + (size_t)(m0 + rr) * lda + k0 + c8;
            __builtin_amdgcn_global_load_lds((GAS*)ga, (LAS*)&As[buf][(w + 4 * i) * 512], 16, 0, 0);
        }
        const unsigned short* gb = Bm + (size_t)(n0 + w * 16 + l4) * K + k0 + c8;
        __builtin_amdgcn_global_load_lds((GAS*)gb, (LAS*)&Bs[buf][w * 512], 16, 0, 0);
    };

    stage(0, 0);
    __syncthreads();
    int buf = 0;
    for (int ks = 0; ks < nk; ++ks) {
        if (ks + 1 < nk) stage(buf ^ 1, (ks + 1) * 32);
        bfx8 af[4], bfr[2];
        #pragma unroll
        for (int mi = 0; mi < 4; mi++) af[mi] = *(const bfx8*)&As[buf][(wr * 64 + mi * 16 + r16) * 32 + kk];
        #pragma unroll
        for (int ni = 0; ni < 2; ni++) bfr[ni] = *(const bfx8*)&Bs[buf][(wc * 32 + ni * 16 + r16) * 32 + kk];
        #pragma unroll
        for (int mi = 0; mi < 4; mi++)
            #pragma unroll
            for (int ni = 0; ni < 2; ni++)
                acc[mi][ni] = __builtin_amdgcn_mfma_f32_16x16x32_bf16(bfr[ni], af[mi], acc[mi][ni], 0, 0, 0);
        __syncthreads();
        buf ^= 1;
    }

    #pragma unroll
    for (int mi = 0; mi < 4; mi++) {
        int m = m0 + wr * 64 + mi * 16 + r16;
        #pragma unroll
        for (int ni = 0; ni < 2; ni++) {
            int n = n0 + wc * 32 + ni * 16 + rg * 4;
            ushort4 o;
            #pragma unroll
            for (int j = 0; j < 4; ++j) {
                float v = acc[mi][ni][j];
                if (EPI == 1) { v = fmaxf(v, 0.0f); v *= v; }
                ((unsigned short*)&o)[j] = f2b(v);
            }
            *(ushort4*)(C + (size_t)m * ldc + n) = o;
        }
    }
}

// ---------------- gemm4 fused with final, 64x64 tiles, transposed mfma, float4 epilogue ---
__global__ __launch_bounds__(256) void gemm4f64(const unsigned short* __restrict__ A,
                                                const unsigned short* __restrict__ Wm,
                                                const float* __restrict__ x,
                                                float* __restrict__ out) {
    __shared__ unsigned short As[2][64 * 32];
    __shared__ unsigned short Bu[2][64 * 32];
    __shared__ unsigned short Bg[2][64 * 32];
    const int hw = blockIdx.y * gridDim.x + blockIdx.x;
    const int lg = xcd_swz(hw, gridDim.x * gridDim.y);   // 16 x 256 = 4096 blocks
    const int n0 = (lg & 15) * 64;            // u col block within 1024
    const int m0 = (lg >> 4) * 64;
    const int tid = threadIdx.x;
    const int lane = tid & 63;
    const int w = tid >> 6;
    const int wr = w >> 1, wc = w & 1;
    const int r16 = lane & 15;
    const int rg = lane >> 4;
    const int kk = rg * 8;
    const int l4 = lane >> 2;
    const int c8 = (lane & 3) * 8;
    fx4 accu[2][2] = {};
    fx4 accg[2][2] = {};

    auto stage = [&](int buf, int k0) {
        int rr = w * 16 + l4;
        const unsigned short* ga = A + (size_t)(m0 + rr) * TDR + k0 + c8;
        const unsigned short* gu = Wm + (size_t)(n0 + rr) * TDR + k0 + c8;
        const unsigned short* gg = Wm + (size_t)(1024 + n0 + rr) * TDR + k0 + c8;
        __builtin_amdgcn_global_load_lds((GAS*)ga, (LAS*)&As[buf][w * 512], 16, 0, 0);
        __builtin_amdgcn_global_load_lds((GAS*)gu, (LAS*)&Bu[buf][w * 512], 16, 0, 0);
        __builtin_amdgcn_global_load_lds((GAS*)gg, (LAS*)&Bg[buf][w * 512], 16, 0, 0);
    };

    stage(0, 0);
    __syncthreads();
    int buf = 0;
    for (int ks = 0; ks < 8; ++ks) {          // K = 256
        if (ks + 1 < 8) stage(buf ^ 1, (ks + 1) * 32);
        bfx8 af[2], bu[2], bg[2];
        #pragma unroll
        for (int mi = 0; mi < 2; mi++) af[mi] = *(const bfx8*)&As[buf][(wr * 32 + mi * 16 + r16) * 32 + kk];
        #pragma unroll
        for (int ni = 0; ni < 2; ni++) {
            bu[ni] = *(const bfx8*)&Bu[buf][(wc * 32 + ni * 16 + r16) * 32 + kk];
            bg[ni] = *(const bfx8*)&Bg[buf][(wc * 32 + ni * 16 + r16) * 32 + kk];
        }
        #pragma unroll
        for (int mi = 0; mi < 2; mi++)
            #pragma unroll
            for (int ni = 0; ni < 2; ni++) {
                accu[mi][ni] = __builtin_amdgcn_mfma_f32_16x16x32_bf16(bu[ni], af[mi], accu[mi][ni], 0, 0, 0);
                accg[mi][ni] = __builtin_amdgcn_mfma_f32_16x16x32_bf16(bg[ni], af[mi], accg[mi][ni], 0, 0, 0);
            }
        __syncthreads();
        buf ^= 1;
    }

    #pragma unroll
    for (int mi = 0; mi < 2; mi++) {
        int m = m0 + wr * 32 + mi * 16 + r16;
        #pragma unroll
        for (int ni = 0; ni < 2; ni++) {
            int n = n0 + wc * 32 + ni * 16 + rg * 4;
            size_t base = (size_t)m * TC + n;
            float4 xv = *(const float4*)(x + base);
            float4 o;
            #pragma unroll
            for (int j = 0; j < 4; ++j) {
                float u = accu[mi][ni][j];
                float g = accg[mi][ni][j];
                (&o.x)[j] = (&xv.x)[j] + u * (g * sigm(g));
            }
            *(float4*)(out + base) = o;
        }
    }
}

// ---------------- fused post (R11-proven): q/k RMSNorm+RoPE, p=sigm(k)*v, 32-t seg sums --
__global__ __launch_bounds__(256) void post64(unsigned short* __restrict__ qkv,
                                              const float* __restrict__ ct,
                                              const float* __restrict__ st,
                                              float* __restrict__ part,
                                              int ntiles, int nseg) {
    const int blk = blockIdx.x;
    const int tile = blk % ntiles, h = blk / ntiles;
    const size_t slab = (size_t)ntiles * 64 * 128;
    const int g = threadIdx.x >> 4, l16 = threadIdx.x & 15;
    const int d0 = l16 * 4;
    unsigned short* qs = qkv + (size_t)h * slab;
    unsigned short* ks = qkv + (size_t)(16 + h) * slab;
    unsigned short* vs = qkv + (size_t)(32 + h) * slab;
    __shared__ float psum[2][16][128];
    float acc0[2][4] = {};
    float acc1[2][4] = {};

    #pragma unroll
    for (int p = 0; p < 4; ++p) {
        const int r = tile * 64 + p * 16 + g;      // row within chunk
        const int t = r & (TT - 1);                // time within batch (rope index)
        const size_t lo = (size_t)r * 128 + d0, hi = lo + 64;
        ushort4 q1 = *(const ushort4*)(qs + lo);
        ushort4 q2 = *(const ushort4*)(qs + hi);
        ushort4 k1 = *(const ushort4*)(ks + lo);
        ushort4 k2 = *(const ushort4*)(ks + hi);
        float qa[8] = {b2f(q1.x), b2f(q1.y), b2f(q1.z), b2f(q1.w),
                       b2f(q2.x), b2f(q2.y), b2f(q2.z), b2f(q2.w)};
        float ka[8] = {b2f(k1.x), b2f(k1.y), b2f(k1.z), b2f(k1.w),
                       b2f(k2.x), b2f(k2.y), b2f(k2.z), b2f(k2.w)};
        float ssq = 0.0f, ssk = 0.0f;
        #pragma unroll
        for (int j = 0; j < 8; ++j) { ssq += qa[j] * qa[j]; ssk += ka[j] * ka[j]; }
        #pragma unroll
        for (int o = 8; o > 0; o >>= 1) {
            ssq += __shfl_xor(ssq, o);
            ssk += __shfl_xor(ssk, o);
        }
        float qsc = rsqrtf(ssq * (1.0f / TDH) + 1.1920929e-7f);
        float ksc = rsqrtf(ssk * (1.0f / TDH) + 1.1920929e-7f);
        float c[4], s[4];
        if (l16 < 8) {
            float4 cv = *(const float4*)(ct + t * 32 + d0);
            float4 sv = *(const float4*)(st + t * 32 + d0);
            c[0] = cv.x; c[1] = cv.y; c[2] = cv.z; c[3] = cv.w;
            s[0] = sv.x; s[1] = sv.y; s[2] = sv.z; s[3] = sv.w;
        } else {
            c[0] = c[1] = c[2] = c[3] = 1.0f;
            s[0] = s[1] = s[2] = s[3] = 0.0f;
        }
        ushort4 v1 = *(const ushort4*)(vs + lo);
        ushort4 v2 = *(const ushort4*)(vs + hi);
        float va[8] = {b2f(v1.x), b2f(v1.y), b2f(v1.z), b2f(v1.w),
                       b2f(v2.x), b2f(v2.y), b2f(v2.z), b2f(v2.w)};
        ushort4 qo1, qo2, po1, po2;
        unsigned short* qo1p = (unsigned short*)&qo1;
        unsigned short* qo2p = (unsigned short*)&qo2;
        unsigned short* po1p = (unsigned short*)&po1;
        unsigned short* po2p = (unsigned short*)&po2;
        const int h2 = p >> 1;
        #pragma unroll
        for (int j = 0; j < 4; ++j) {
            float z1q = qa[j] * qsc, z2q = qa[4 + j] * qsc;
            float z1k = ka[j] * ksc, z2k = ka[4 + j] * ksc;
            float qlo = z1q * c[j] + z2q * s[j];
            float qhi = z2q * c[j] - z1q * s[j];
            float klo = z1k * c[j] + z2k * s[j];
            float khi = z2k * c[j] - z1k * s[j];
            float plo = sigm(klo) * va[j];
            float phi = sigm(khi) * va[4 + j];
            qo1p[j] = f2b(qlo); qo2p[j] = f2b(qhi);
            po1p[j] = f2b(plo); po2p[j] = f2b(phi);
            acc0[h2][j] += plo;
            acc1[h2][j] += phi;
        }
        *(ushort4*)(qs + lo) = qo1;
        *(ushort4*)(qs + hi) = qo2;
        *(ushort4*)(ks + lo) = po1;   // p overwrites k (k dead afterwards)
        *(ushort4*)(ks + hi) = po2;
    }
    #pragma unroll
    for (int h2 = 0; h2 < 2; ++h2) {
        *(float4*)&psum[h2][g][d0]      = *(float4*)acc0[h2];
        *(float4*)&psum[h2][g][64 + d0] = *(float4*)acc1[h2];
    }
    __syncthreads();
    const int h2 = threadIdx.x >> 7, d = threadIdx.x & 127;
    float tot = 0.0f;
    #pragma unroll
    for (int gg = 0; gg < 16; ++gg) tot += psum[h2][gg][d];
    part[((size_t)h * nseg + tile * 2 + h2) * 128 + d] = tot;
}

// ---------------- phase B: exclusive prefix, one chain per (h, batch, d) ----------------
__global__ __launch_bounds__(256) void scanB2(float* __restrict__ part, int cb) {
    int idx = blockIdx.x * 256 + threadIdx.x;   // < TNH*cb*128
    int d = idx & 127;
    int hb = idx >> 7;                           // h*cb + batch
    int batch = hb % cb;
    int h = hb / cb;
    int nseg = cb * 128;
    size_t base = ((size_t)h * nseg + (size_t)batch * 128) * 128 + d;
    float run = 0.0f;
    #pragma unroll
    for (int r = 0; r < 4; ++r) {
        float v[32];
        #pragma unroll
        for (int i = 0; i < 32; ++i) v[i] = part[base + (size_t)(r * 32 + i) * 128];
        #pragma unroll
        for (int i = 0; i < 32; ++i) { float tv = v[i]; v[i] = run; run += tv; }
        #pragma unroll
        for (int i = 0; i < 32; ++i) part[base + (size_t)(r * 32 + i) * 128] = v[i];
    }
}

// ---------------- phase C: y = relu(q) * cumsum(p) -> y row-major ----------
__global__ __launch_bounds__(256) void scanC3(const unsigned short* __restrict__ qkv,
                                              const float* __restrict__ part,
                                              unsigned short* __restrict__ y,
                                              int nsegblk, int nseg) {
    const int bseg = blockIdx.x % nsegblk, h = blockIdx.x / nsegblk;
    const size_t slab = (size_t)nseg * 32 * 128;
    const int g = threadIdx.x >> 4, l16 = threadIdx.x & 15;
    const int seg = bseg * 16 + g;
    const int d0 = l16 * 8;
    const unsigned short* qp = qkv + (size_t)h * slab;
    const unsigned short* pp = qkv + (size_t)(16 + h) * slab;
    float sum[8];
    const float* pb = part + ((size_t)h * nseg + seg) * 128 + d0;
    *(float4*)&sum[0] = *(const float4*)pb;
    *(float4*)&sum[4] = *(const float4*)(pb + 4);
    #pragma unroll 4
    for (int i = 0; i < 32; ++i) {
        int t = seg * 32 + i;
        size_t off = (size_t)t * 128 + d0;
        bfx8 pv = *(const bfx8*)(pp + off);
        bfx8 qv = *(const bfx8*)(qp + off);
        bfx8 ov;
        #pragma unroll
        for (int j = 0; j < 8; ++j) {
            sum[j] += b2f((unsigned short)pv[j]);
            float q = b2f((unsigned short)qv[j]);
            ov[j] = (short)f2b(fmaxf(q, 0.0f) * sum[j]);
        }
        *(bfx8*)(y + (size_t)t * 2048 + h * 128 + d0) = ov;
    }
}

extern "C" void kernel_launch(void* const* d_in, const int* in_sizes, int n_in,
                              void* d_out, int out_size, void* d_ws, size_t ws_size,
                              hipStream_t stream) {
    (void)in_sizes; (void)n_in; (void)out_size;
    const float* x    = (const float*)d_in[0];
    const float* wq1  = (const float*)d_in[1];   // [256,1024]
    const float* wq2  = (const float*)d_in[2];   // [6144,256]
    const float* wc1  = (const float*)d_in[3];   // [256,2048]
    const float* wc2  = (const float*)d_in[4];   // [2048,256]
    float* out = (float*)d_out;

    // pick batches-per-chunk CB by available workspace
    auto need = [](int cb) -> size_t {
        size_t o = 0;
        auto a = [&](size_t b) { o = (o + 255) & ~(size_t)255; o += b; };
        size_t qkvsz = (size_t)cb * RB * 6144 * 2;
        size_t xnsz  = (size_t)ROWS * TC * 2;
        a(qkvsz > xnsz ? qkvsz : xnsz);                 // pool
        a((size_t)ROWS * TDR * 2);                       // hbuf
        a((size_t)TDR * TC * 2);                         // w1b
        a((size_t)3 * TDQKV * TDR * 2);                  // w2b
        a((size_t)TDR * TDQKV * 2);                      // wp1b
        a((size_t)2 * TC * TDR * 2);                     // wp2b
        a((size_t)TT * 32 * 4);                          // ct
        a((size_t)TT * 32 * 4);                          // st
        a((size_t)TNH * (cb * RB / 32) * 128 * 4);       // part
        return o;
    };
    int CB = (ws_size >= need(4)) ? 4 : (ws_size >= need(2)) ? 2 : 1;
    const int TR = CB * RB;            // rows per chunk
    const int NCH = TB / CB;           // chunks
    const int nseg = TR / 32;
    const int ntiles = TR / 64;

    char* ws = (char*)d_ws;
    size_t off = 0;
    auto alloc = [&](size_t bytes) -> void* {
        off = (off + 255) & ~(size_t)255;
        void* p = ws + off;
        off += bytes;
        return p;
    };
    size_t qkvsz = (size_t)TR * 6144 * 2;
    size_t xnsz  = (size_t)ROWS * TC * 2;
    char* pool = (char*)alloc(qkvsz > xnsz ? qkvsz : xnsz);
    unsigned short* qkvb = (unsigned short*)pool;              // head-major: 48 slabs [TR][128]
    unsigned short* xn   = (unsigned short*)pool;              // alias (ROWS x 1024)
    unsigned short* t1   = (unsigned short*)pool;              // alias (ROWS x 256)
    unsigned short* hbuf = (unsigned short*)alloc((size_t)ROWS * TDR * 2);
    unsigned short* w1b  = (unsigned short*)alloc((size_t)TDR * TC * 2);
    unsigned short* w2b  = (unsigned short*)alloc((size_t)3 * TDQKV * TDR * 2);
    unsigned short* wp1b = (unsigned short*)alloc((size_t)TDR * TDQKV * 2);
    unsigned short* wp2b = (unsigned short*)alloc((size_t)2 * TC * TDR * 2);
    float* ct   = (float*)alloc((size_t)TT * 32 * 4);
    float* st   = (float*)alloc((size_t)TT * 32 * 4);
    float* part = (float*)alloc((size_t)TNH * nseg * 128 * 4);
    unsigned short* ybuf = (unsigned short*)d_out;             // y lives in d_out (bf16 16384x2048)

    // fused setup (one launch)
    setup_all<<<3328, 256, 0, stream>>>(wq1, w1b, wq2, w2b, wc1, wp1b, wc2, wp2b, ct, st);

    // all-rows: rmsnorm + gemm1 (xn -> h) with relu^2
    rmsnorm_x<<<ROWS, 256, 0, stream>>>(x, xn);
    gemm_sk<1, 4><<<(ROWS / 128) * (TDR / 64), 256, 0, stream>>>(
        xn, TC, w1b, hbuf, TDR, TC);

    // per-chunk: gemm2 (head-major scatter) -> post64 -> scanB2 -> scanC3
    for (int c = 0; c < NCH; ++c) {
        gemm2k<<<dim3(6144 / 128, TR / 128), 256, 0, stream>>>(
            hbuf + (size_t)c * TR * TDR, w2b, qkvb, TDR, (size_t)TR * 128);
        post64<<<TNH * ntiles, 256, 0, stream>>>(qkvb, ct, st, part, ntiles, nseg);
        scanB2<<<(TNH * CB * 128) / 256, 256, 0, stream>>>(part, CB);
        scanC3<<<TNH * (nseg / 16), 256, 0, stream>>>(
            qkvb, part, ybuf + (size_t)c * TR * 2048, nseg / 16, nseg);
    }

    // all-rows tail: gemm3 (y -> t1), fused gemm4+final -> f32 out
    gemm_sk<0, 4><<<(ROWS / 128) * (TDR / 64), 256, 0, stream>>>(
        ybuf, 2048, wp1b, t1, TDR, TDQKV);
    gemm4f64<<<dim3(TC / 64, ROWS / 64), 256, 0, stream>>>(t1, wp2b, x, out);
}